// Round 3
// baseline (116.009 us; speedup 1.0000x reference)
//
#include <hip/hip_runtime.h>
#include <hip/hip_bf16.h>

#define MM 128      // molecules
#define NA 21       // atoms
#define DD 210      // descriptors
#define DP 224      // padded descriptors (multiple of 32)
#define TT 4096     // training points

#define QF   0.22360679774997896f   // sqrt(5)/10
#define Q2F  0.05f                  // Q^2 = 5/100
#define K0E  0.016666666666666666f  // 5/(3*SIG^2) = 1/60
#define INVQ 4.47213595499958f      // 1/Q

// ---- workspace layout (float offsets) ----
#define OFF_TRP 0                       // [TT][DP]
#define OFF_JXP (OFF_TRP + TT*DP)       // [TT][DP]
#define OFF_W1  (OFF_JXP + TT*DP)       // [MM][TT]
#define OFF_W2  (OFF_W1 + MM*TT)        // [MM][TT]
#define OFF_XSP (OFF_W2 + MM*TT)        // [MM][DP]
#define OFF_NT  (OFF_XSP + MM*DP)       // [TT]
#define OFF_CT  (OFF_NT + TT)           // [TT]
#define OFF_NM  (OFF_CT + TT)           // [MM]
#define OFF_A1  (OFF_NM + MM)           // [MM][DP]  (zeroed by k0 tail blocks)
#define OFF_A2  (OFF_A1 + MM*DP)        // [MM][DP]
#define OFF_S1  (OFF_A2 + MM*DP)        // [MM]
#define OFF_E   (OFF_S1 + MM)           // [MM]
#define ZERO_FLOATS (MM*DP*2 + MM*2)    // = 57600 = 225 * 256
#define ZBLOCKS 225

// ---------- K0 hybrid: [0,TT) pad+nt/ct | [TT,TT+MM) descriptors | zero tail ----------
__global__ __launch_bounds__(256) void k0_fused(
        const float* __restrict__ tr, const float* __restrict__ jx,
        const float* __restrict__ Rs,
        float* __restrict__ trp, float* __restrict__ jxp,
        float* __restrict__ nt, float* __restrict__ ct,
        float* __restrict__ xsp, float* __restrict__ nmg,
        float* __restrict__ zbase) {
    int b = blockIdx.x, tid = threadIdx.x;
    __shared__ float red0[4], red1[4];
    __shared__ float Rl[64];

    if (b < TT) {
        // pad/copy one training row + row reductions nt=|xt|^2, ct=xt.Jx
        int t = b;
        float v1 = 0.f, v2 = 0.f;
        if (tid < DD) { v1 = tr[t * DD + tid]; v2 = jx[t * DD + tid]; }
        if (tid < DP) { trp[t * DP + tid] = v1; jxp[t * DP + tid] = v2; }
        float sn = v1 * v1, sc = v1 * v2;
        #pragma unroll
        for (int off = 32; off >= 1; off >>= 1) {
            sn += __shfl_xor(sn, off);
            sc += __shfl_xor(sc, off);
        }
        if ((tid & 63) == 0) { red0[tid >> 6] = sn; red1[tid >> 6] = sc; }
        __syncthreads();
        if (tid == 0) {
            nt[t] = red0[0] + red0[1] + red0[2] + red0[3];
            ct[t] = red1[0] + red1[1] + red1[2] + red1[3];
        }
    } else if (b < TT + MM) {
        // descriptors xs[m,d] = 1/dist(pair d), nm = |xs|^2
        int m = b - TT;
        if (tid < NA * 3) Rl[tid] = Rs[m * NA * 3 + tid];
        __syncthreads();
        float v = 0.f;
        if (tid < DP) {
            float x = 0.f;
            if (tid < DD) {
                int d = tid;
                int a = (int)((1.0f + sqrtf(8.0f * (float)d + 1.0f)) * 0.5f);
                while (a * (a - 1) / 2 > d) --a;
                while ((a + 1) * a / 2 <= d) ++a;
                int bb = d - a * (a - 1) / 2;
                float dx = Rl[a * 3 + 0] - Rl[bb * 3 + 0];
                float dy = Rl[a * 3 + 1] - Rl[bb * 3 + 1];
                float dz = Rl[a * 3 + 2] - Rl[bb * 3 + 2];
                x = 1.0f / sqrtf(dx * dx + dy * dy + dz * dz);
            }
            xsp[m * DP + tid] = x;
            v = x * x;
        }
        #pragma unroll
        for (int off = 32; off >= 1; off >>= 1) v += __shfl_xor(v, off);
        if ((tid & 63) == 0) red0[tid >> 6] = v;
        __syncthreads();
        if (tid == 0) nmg[m] = red0[0] + red0[1] + red0[2] + red0[3];
    } else {
        // zero A1/A2/s1/E
        int idx = (b - TT - MM) * 256 + tid;
        zbase[idx] = 0.f;
    }
}

// ---------- K2: phase A -- G1/G2 tiles -> W1,W2, s1, E ----------
// tile: BM=32 (m) x BT=64 (t), BD=32 k-chunk, 128 threads, micro 4m x 4t
#define BM 32
#define BT 64
#define BD 32
__global__ __launch_bounds__(128) void k2_phaseA(
        const float* __restrict__ xsp, const float* __restrict__ trp,
        const float* __restrict__ jxp, const float* __restrict__ nm,
        const float* __restrict__ nt, const float* __restrict__ ct,
        float* __restrict__ W1, float* __restrict__ W2,
        float* __restrict__ s1g, float* __restrict__ Eg) {
    __shared__ __align__(16) float As[BD][BM + 4];   // stride 36
    __shared__ __align__(16) float Ts[BD][BT + 4];   // stride 68
    __shared__ __align__(16) float Js[BD][BT + 4];
    int tid = threadIdx.x;
    int t0 = blockIdx.x * BT;
    int m0 = blockIdx.y * BM;
    int ty = tid >> 4;      // 0..7 -> m micro row * 4
    int tx = tid & 15;      // 0..15 -> t micro col * 4
    float g1[4][4] = {{0.f}};
    float g2[4][4] = {{0.f}};
    int amm = tid >> 2;     // 0..31
    int aseg = tid & 3;     // 0..3  -> 8 cols
    int ttt = tid >> 1;     // 0..63
    int tseg = tid & 1;     // 0..1  -> 16 cols

    for (int dk = 0; dk < DP; dk += BD) {
        const float* ap = xsp + (m0 + amm) * DP + dk + aseg * 8;
        float4 av0 = *(const float4*)(ap);
        float4 av1 = *(const float4*)(ap + 4);
        const float* tp = trp + (t0 + ttt) * DP + dk + tseg * 16;
        const float* jp = jxp + (t0 + ttt) * DP + dk + tseg * 16;
        float4 tv0 = *(const float4*)(tp);
        float4 tv1 = *(const float4*)(tp + 4);
        float4 tv2 = *(const float4*)(tp + 8);
        float4 tv3 = *(const float4*)(tp + 12);
        float4 jv0 = *(const float4*)(jp);
        float4 jv1 = *(const float4*)(jp + 4);
        float4 jv2 = *(const float4*)(jp + 8);
        float4 jv3 = *(const float4*)(jp + 12);
        __syncthreads();
        As[aseg * 8 + 0][amm] = av0.x; As[aseg * 8 + 1][amm] = av0.y;
        As[aseg * 8 + 2][amm] = av0.z; As[aseg * 8 + 3][amm] = av0.w;
        As[aseg * 8 + 4][amm] = av1.x; As[aseg * 8 + 5][amm] = av1.y;
        As[aseg * 8 + 6][amm] = av1.z; As[aseg * 8 + 7][amm] = av1.w;
        int c0 = tseg * 16;
        Ts[c0 + 0][ttt] = tv0.x;  Ts[c0 + 1][ttt] = tv0.y;  Ts[c0 + 2][ttt] = tv0.z;  Ts[c0 + 3][ttt] = tv0.w;
        Ts[c0 + 4][ttt] = tv1.x;  Ts[c0 + 5][ttt] = tv1.y;  Ts[c0 + 6][ttt] = tv1.z;  Ts[c0 + 7][ttt] = tv1.w;
        Ts[c0 + 8][ttt] = tv2.x;  Ts[c0 + 9][ttt] = tv2.y;  Ts[c0 + 10][ttt] = tv2.z; Ts[c0 + 11][ttt] = tv2.w;
        Ts[c0 + 12][ttt] = tv3.x; Ts[c0 + 13][ttt] = tv3.y; Ts[c0 + 14][ttt] = tv3.z; Ts[c0 + 15][ttt] = tv3.w;
        Js[c0 + 0][ttt] = jv0.x;  Js[c0 + 1][ttt] = jv0.y;  Js[c0 + 2][ttt] = jv0.z;  Js[c0 + 3][ttt] = jv0.w;
        Js[c0 + 4][ttt] = jv1.x;  Js[c0 + 5][ttt] = jv1.y;  Js[c0 + 6][ttt] = jv1.z;  Js[c0 + 7][ttt] = jv1.w;
        Js[c0 + 8][ttt] = jv2.x;  Js[c0 + 9][ttt] = jv2.y;  Js[c0 + 10][ttt] = jv2.z; Js[c0 + 11][ttt] = jv2.w;
        Js[c0 + 12][ttt] = jv3.x; Js[c0 + 13][ttt] = jv3.y; Js[c0 + 14][ttt] = jv3.z; Js[c0 + 15][ttt] = jv3.w;
        __syncthreads();
        #pragma unroll
        for (int dd = 0; dd < BD; ++dd) {
            float4 a  = *(const float4*)&As[dd][ty * 4];
            float4 tv = *(const float4*)&Ts[dd][tx * 4];
            float4 jv = *(const float4*)&Js[dd][tx * 4];
            float am[4] = {a.x, a.y, a.z, a.w};
            float t4[4] = {tv.x, tv.y, tv.z, tv.w};
            float j4[4] = {jv.x, jv.y, jv.z, jv.w};
            #pragma unroll
            for (int i = 0; i < 4; ++i) {
                #pragma unroll
                for (int k = 0; k < 4; ++k) {
                    g1[i][k] = fmaf(am[i], t4[k], g1[i][k]);
                    g2[i][k] = fmaf(am[i], j4[k], g2[i][k]);
                }
            }
        }
    }

    float nmv[4], ntv[4], ctv[4];
    #pragma unroll
    for (int i = 0; i < 4; ++i) nmv[i] = nm[m0 + ty * 4 + i];
    #pragma unroll
    for (int k = 0; k < 4; ++k) { ntv[k] = nt[t0 + tx * 4 + k]; ctv[k] = ct[t0 + tx * 4 + k]; }

    float s1loc[4] = {0.f, 0.f, 0.f, 0.f};
    float eloc[4]  = {0.f, 0.f, 0.f, 0.f};
    #pragma unroll
    for (int i = 0; i < 4; ++i) {
        float w1v[4], w2v[4];
        #pragma unroll
        for (int k = 0; k < 4; ++k) {
            float d2 = Q2F * (nmv[i] + ntv[k] - 2.f * g1[i][k]);
            float xd = sqrtf(fmaxf(d2, 0.f));
            float e  = K0E * __expf(-xd);
            float dv = QF * (g2[i][k] - ctv[k]);
            float w1 = e * dv;
            float w2 = e * (1.f + xd);
            w1v[k] = w1; w2v[k] = w2;
            s1loc[i] += w1;
            eloc[i]  = fmaf(w2, dv, eloc[i]);
        }
        float4 o1 = {w1v[0], w1v[1], w1v[2], w1v[3]};
        float4 o2 = {w2v[0], w2v[1], w2v[2], w2v[3]};
        *(float4*)&W1[(m0 + ty * 4 + i) * TT + t0 + tx * 4] = o1;
        *(float4*)&W2[(m0 + ty * 4 + i) * TT + t0 + tx * 4] = o2;
    }
    #pragma unroll
    for (int off = 8; off >= 1; off >>= 1) {
        #pragma unroll
        for (int i = 0; i < 4; ++i) {
            s1loc[i] += __shfl_xor(s1loc[i], off);
            eloc[i]  += __shfl_xor(eloc[i], off);
        }
    }
    if (tx == 0) {
        #pragma unroll
        for (int i = 0; i < 4; ++i) {
            atomicAdd(&s1g[m0 + ty * 4 + i], s1loc[i]);
            atomicAdd(&Eg[m0 + ty * 4 + i], eloc[i]);
        }
    }
}

// ---------- K3 v2: phase B as register-tiled GEMM ----------
// block: 256 threads, computes 16m x 224d over a 64-t chunk for BOTH arrays.
// W tile staged once in LDS (8 KB), inner loop barrier-free.
// thread: mg=tid/56 picks 4 m's, dcol=(tid%56)*4 picks 4 d's -> 4x4 float micro x2.
#define KB3 64
__global__ __launch_bounds__(256, 2) void k3_phaseB(
        const float* __restrict__ W1, const float* __restrict__ W2,
        const float* __restrict__ trp, const float* __restrict__ jxp,
        float* __restrict__ A1, float* __restrict__ A2) {
    __shared__ __align__(16) float Wl1[16][KB3];
    __shared__ __align__(16) float Wl2[16][KB3];
    int tid = threadIdx.x;
    int t0 = blockIdx.x * KB3;
    int m0 = blockIdx.y * 16;

    {   // cooperative W tile load: 16 rows x 64 cols = 256 float4 per array
        int m = tid >> 4, tc = (tid & 15) * 4;
        float4 w1 = *(const float4*)&W1[(m0 + m) * TT + t0 + tc];
        float4 w2 = *(const float4*)&W2[(m0 + m) * TT + t0 + tc];
        *(float4*)&Wl1[m][tc] = w1;
        *(float4*)&Wl2[m][tc] = w2;
    }
    __syncthreads();
    if (tid >= 224) return;   // no barriers below

    int dcol = (tid % 56) * 4;
    int mg = tid / 56;        // 0..3 -> m = mg*4 + mi

    float4 acc1[4], acc2[4];
    #pragma unroll
    for (int i = 0; i < 4; ++i) {
        acc1[i] = {0.f, 0.f, 0.f, 0.f};
        acc2[i] = {0.f, 0.f, 0.f, 0.f};
    }

    for (int tq = 0; tq < KB3 / 4; ++tq) {
        float4 x1[4], x2[4];
        #pragma unroll
        for (int tt = 0; tt < 4; ++tt) {
            int trow = (t0 + tq * 4 + tt) * DP + dcol;
            x1[tt] = *(const float4*)&trp[trow];
            x2[tt] = *(const float4*)&jxp[trow];
        }
        #pragma unroll
        for (int mi = 0; mi < 4; ++mi) {
            float4 w1 = *(const float4*)&Wl1[mg * 4 + mi][tq * 4];
            float4 w2 = *(const float4*)&Wl2[mg * 4 + mi][tq * 4];
            float w1a[4] = {w1.x, w1.y, w1.z, w1.w};
            float w2a[4] = {w2.x, w2.y, w2.z, w2.w};
            #pragma unroll
            for (int tt = 0; tt < 4; ++tt) {
                acc1[mi].x = fmaf(w1a[tt], x1[tt].x, acc1[mi].x);
                acc1[mi].y = fmaf(w1a[tt], x1[tt].y, acc1[mi].y);
                acc1[mi].z = fmaf(w1a[tt], x1[tt].z, acc1[mi].z);
                acc1[mi].w = fmaf(w1a[tt], x1[tt].w, acc1[mi].w);
                acc2[mi].x = fmaf(w2a[tt], x2[tt].x, acc2[mi].x);
                acc2[mi].y = fmaf(w2a[tt], x2[tt].y, acc2[mi].y);
                acc2[mi].z = fmaf(w2a[tt], x2[tt].z, acc2[mi].z);
                acc2[mi].w = fmaf(w2a[tt], x2[tt].w, acc2[mi].w);
            }
        }
    }

    #pragma unroll
    for (int mi = 0; mi < 4; ++mi) {
        float* p1 = &A1[(m0 + mg * 4 + mi) * DP + dcol];
        float* p2 = &A2[(m0 + mg * 4 + mi) * DP + dcol];
        atomicAdd(p1 + 0, acc1[mi].x);
        atomicAdd(p1 + 1, acc1[mi].y);
        atomicAdd(p1 + 2, acc1[mi].z);
        atomicAdd(p1 + 3, acc1[mi].w);
        atomicAdd(p2 + 0, acc2[mi].x);
        atomicAdd(p2 + 1, acc2[mi].y);
        atomicAdd(p2 + 2, acc2[mi].z);
        atomicAdd(p2 + 3, acc2[mi].w);
    }
}

// ---------- K4: final forces + energies ----------
__global__ __launch_bounds__(256) void k4_final(
        const float* __restrict__ Rs, const float* __restrict__ xsp,
        const float* __restrict__ A1, const float* __restrict__ A2,
        const float* __restrict__ s1g, const float* __restrict__ Eg,
        float* __restrict__ out) {
    int m = blockIdx.x, tid = threadIdx.x;
    __shared__ float fxs[DD];
    __shared__ float Rl[64];
    if (tid < NA * 3) Rl[tid] = Rs[m * NA * 3 + tid];
    float s1v = s1g[m];
    if (tid < DD)
        fxs[tid] = QF * xsp[m * DP + tid] * s1v - QF * A1[m * DP + tid] - A2[m * DP + tid];
    __syncthreads();
    if (tid < NA * 3) {
        int b = tid / 3, c = tid - b * 3;
        float acc = 0.f;
        #pragma unroll
        for (int a = 0; a < NA; ++a) {
            if (a == b) continue;
            int hi = a > b ? a : b, lo = a > b ? b : a;
            int d = hi * (hi - 1) / 2 + lo;
            float dx = Rl[a * 3 + 0] - Rl[b * 3 + 0];
            float dy = Rl[a * 3 + 1] - Rl[b * 3 + 1];
            float dz = Rl[a * 3 + 2] - Rl[b * 3 + 2];
            float r2 = dx * dx + dy * dy + dz * dz;
            float ir = 1.0f / sqrtf(r2);
            float w = fxs[d] * ir * ir * ir;
            float comp = (c == 0) ? dx : ((c == 1) ? dy : dz);
            acc = fmaf(w, comp, acc);
        }
        out[MM + m * NA * 3 + tid] = acc;
    }
    if (tid == 64) out[m] = Eg[m] * INVQ;
}

extern "C" void kernel_launch(void* const* d_in, const int* in_sizes, int n_in,
                              void* d_out, int out_size, void* d_ws, size_t ws_size,
                              hipStream_t stream) {
    const float* Rs = (const float*)d_in[0];
    const float* tr = (const float*)d_in[1];
    const float* jx = (const float*)d_in[2];
    float* out = (float*)d_out;
    float* ws = (float*)d_ws;

    float* trp = ws + OFF_TRP;
    float* jxp = ws + OFF_JXP;
    float* W1  = ws + OFF_W1;
    float* W2  = ws + OFF_W2;
    float* xsp = ws + OFF_XSP;
    float* nt  = ws + OFF_NT;
    float* ct  = ws + OFF_CT;
    float* nm  = ws + OFF_NM;
    float* A1  = ws + OFF_A1;
    float* A2  = ws + OFF_A2;
    float* s1  = ws + OFF_S1;
    float* Eg  = ws + OFF_E;

    k0_fused<<<TT + MM + ZBLOCKS, 256, 0, stream>>>(tr, jx, Rs, trp, jxp, nt, ct, xsp, nm, ws + OFF_A1);
    k2_phaseA<<<dim3(TT / BT, MM / BM), 128, 0, stream>>>(xsp, trp, jxp, nm, nt, ct, W1, W2, s1, Eg);
    k3_phaseB<<<dim3(TT / KB3, MM / 16), 256, 0, stream>>>(W1, W2, trp, jxp, A1, A2);
    k4_final<<<MM, 256, 0, stream>>>(Rs, xsp, A1, A2, s1, Eg, out);
}

// Round 4
// 98.246 us; speedup vs baseline: 1.1808x; 1.1808x over previous
//
#include <hip/hip_runtime.h>
#include <hip/hip_bf16.h>

#define MM 128      // molecules
#define NA 21       // atoms
#define DD 210      // descriptors
#define DP 224      // padded descriptors (multiple of 32)
#define TT 4096     // training points
#define KCH 8       // K-chunks for phase B partials
#define KLEN 512    // TT / KCH

#define QF   0.22360679774997896f   // sqrt(5)/10
#define Q2F  0.05f                  // Q^2 = 5/100
#define K0E  0.016666666666666666f  // 5/(3*SIG^2) = 1/60
#define INVQ 4.47213595499958f      // 1/Q

// ---- workspace layout (float offsets) ----
#define OFF_TRP 0                       // [TT][DP]
#define OFF_JXP (OFF_TRP + TT*DP)       // [TT][DP]
#define OFF_W1  (OFF_JXP + TT*DP)       // [MM][TT]
#define OFF_W2  (OFF_W1 + MM*TT)        // [MM][TT]
#define OFF_XSP (OFF_W2 + MM*TT)        // [MM][DP]
#define OFF_NT  (OFF_XSP + MM*DP)       // [TT]
#define OFF_CT  (OFF_NT + TT)           // [TT]
#define OFF_NM  (OFF_CT + TT)           // [MM]
#define OFF_S1  (OFF_NM + MM)           // [MM]  (zeroed by k0 tail block)
#define OFF_E   (OFF_S1 + MM)           // [MM]  (zeroed by k0 tail block)
#define OFF_P1  (OFF_E + MM)            // [KCH][MM][DP]
#define OFF_P2  (OFF_P1 + KCH*MM*DP)    // [KCH][MM][DP]
// total = 3,379,584 floats = 13.5 MB

// ---------- K0 hybrid: [0,TT) pad+nt/ct | [TT,TT+MM) descriptors | 1 zero block ----------
__global__ __launch_bounds__(256) void k0_fused(
        const float* __restrict__ tr, const float* __restrict__ jx,
        const float* __restrict__ Rs,
        float* __restrict__ trp, float* __restrict__ jxp,
        float* __restrict__ nt, float* __restrict__ ct,
        float* __restrict__ xsp, float* __restrict__ nmg,
        float* __restrict__ zbase) {
    int b = blockIdx.x, tid = threadIdx.x;
    __shared__ float red0[4], red1[4];
    __shared__ float Rl[64];

    if (b < TT) {
        int t = b;
        float v1 = 0.f, v2 = 0.f;
        if (tid < DD) { v1 = tr[t * DD + tid]; v2 = jx[t * DD + tid]; }
        if (tid < DP) { trp[t * DP + tid] = v1; jxp[t * DP + tid] = v2; }
        float sn = v1 * v1, sc = v1 * v2;
        #pragma unroll
        for (int off = 32; off >= 1; off >>= 1) {
            sn += __shfl_xor(sn, off);
            sc += __shfl_xor(sc, off);
        }
        if ((tid & 63) == 0) { red0[tid >> 6] = sn; red1[tid >> 6] = sc; }
        __syncthreads();
        if (tid == 0) {
            nt[t] = red0[0] + red0[1] + red0[2] + red0[3];
            ct[t] = red1[0] + red1[1] + red1[2] + red1[3];
        }
    } else if (b < TT + MM) {
        int m = b - TT;
        if (tid < NA * 3) Rl[tid] = Rs[m * NA * 3 + tid];
        __syncthreads();
        float v = 0.f;
        if (tid < DP) {
            float x = 0.f;
            if (tid < DD) {
                int d = tid;
                int a = (int)((1.0f + sqrtf(8.0f * (float)d + 1.0f)) * 0.5f);
                while (a * (a - 1) / 2 > d) --a;
                while ((a + 1) * a / 2 <= d) ++a;
                int bb = d - a * (a - 1) / 2;
                float dx = Rl[a * 3 + 0] - Rl[bb * 3 + 0];
                float dy = Rl[a * 3 + 1] - Rl[bb * 3 + 1];
                float dz = Rl[a * 3 + 2] - Rl[bb * 3 + 2];
                x = 1.0f / sqrtf(dx * dx + dy * dy + dz * dz);
            }
            xsp[m * DP + tid] = x;
            v = x * x;
        }
        #pragma unroll
        for (int off = 32; off >= 1; off >>= 1) v += __shfl_xor(v, off);
        if ((tid & 63) == 0) red0[tid >> 6] = v;
        __syncthreads();
        if (tid == 0) nmg[m] = red0[0] + red0[1] + red0[2] + red0[3];
    } else {
        zbase[tid] = 0.f;   // s1 (128) + E (128), contiguous
    }
}

// ---------- K2: phase A -- G1/G2 tiles -> W1,W2, s1, E ----------
// tile: BM=32 x BT=64, BD=32 k-chunk, 256 threads, micro 4m x 2t
#define BM 32
#define BT 64
#define BD 32
#define TS_STR 70   // Ts/Js LDS stride (2-way max on staging stores, b64-aligned reads)
__global__ __launch_bounds__(256) void k2_phaseA(
        const float* __restrict__ xsp, const float* __restrict__ trp,
        const float* __restrict__ jxp, const float* __restrict__ nm,
        const float* __restrict__ nt, const float* __restrict__ ct,
        float* __restrict__ W1, float* __restrict__ W2,
        float* __restrict__ s1g, float* __restrict__ Eg) {
    __shared__ __align__(16) float As[BD][BM + 4];     // stride 36 (16B-aligned rows)
    __shared__ __align__(16) float Ts[BD][TS_STR];
    __shared__ __align__(16) float Js[BD][TS_STR];
    int tid = threadIdx.x;
    int t0 = blockIdx.x * BT;
    int m0 = blockIdx.y * BM;
    int ty = tid >> 5;      // 0..7  -> m group (4 m each)
    int tx = tid & 31;      // 0..31 -> t pair (2 t each)
    float g1[4][2] = {{0.f}};
    float g2[4][2] = {{0.f}};
    int amm = tid >> 3;     // 0..31 m row for A staging
    int aseg = tid & 7;     // 0..7  -> 4 d's
    int ttt = tid >> 2;     // 0..63 t row for T/J staging
    int tseg = tid & 3;     // 0..3  -> 8 d's

    for (int dk = 0; dk < DP; dk += BD) {
        float4 av = *(const float4*)(xsp + (m0 + amm) * DP + dk + aseg * 4);
        const float* tp = trp + (t0 + ttt) * DP + dk + tseg * 8;
        const float* jp = jxp + (t0 + ttt) * DP + dk + tseg * 8;
        float4 tv0 = *(const float4*)(tp);
        float4 tv1 = *(const float4*)(tp + 4);
        float4 jv0 = *(const float4*)(jp);
        float4 jv1 = *(const float4*)(jp + 4);
        __syncthreads();
        As[aseg * 4 + 0][amm] = av.x; As[aseg * 4 + 1][amm] = av.y;
        As[aseg * 4 + 2][amm] = av.z; As[aseg * 4 + 3][amm] = av.w;
        int c0 = tseg * 8;
        Ts[c0 + 0][ttt] = tv0.x; Ts[c0 + 1][ttt] = tv0.y; Ts[c0 + 2][ttt] = tv0.z; Ts[c0 + 3][ttt] = tv0.w;
        Ts[c0 + 4][ttt] = tv1.x; Ts[c0 + 5][ttt] = tv1.y; Ts[c0 + 6][ttt] = tv1.z; Ts[c0 + 7][ttt] = tv1.w;
        Js[c0 + 0][ttt] = jv0.x; Js[c0 + 1][ttt] = jv0.y; Js[c0 + 2][ttt] = jv0.z; Js[c0 + 3][ttt] = jv0.w;
        Js[c0 + 4][ttt] = jv1.x; Js[c0 + 5][ttt] = jv1.y; Js[c0 + 6][ttt] = jv1.z; Js[c0 + 7][ttt] = jv1.w;
        __syncthreads();
        #pragma unroll
        for (int dd = 0; dd < BD; ++dd) {
            float4 a  = *(const float4*)&As[dd][ty * 4];
            float2 tv = *(const float2*)&Ts[dd][tx * 2];
            float2 jv = *(const float2*)&Js[dd][tx * 2];
            float am[4] = {a.x, a.y, a.z, a.w};
            float t2[2] = {tv.x, tv.y};
            float j2[2] = {jv.x, jv.y};
            #pragma unroll
            for (int i = 0; i < 4; ++i) {
                #pragma unroll
                for (int k = 0; k < 2; ++k) {
                    g1[i][k] = fmaf(am[i], t2[k], g1[i][k]);
                    g2[i][k] = fmaf(am[i], j2[k], g2[i][k]);
                }
            }
        }
    }

    float nmv[4], ntv[2], ctv[2];
    #pragma unroll
    for (int i = 0; i < 4; ++i) nmv[i] = nm[m0 + ty * 4 + i];
    #pragma unroll
    for (int k = 0; k < 2; ++k) { ntv[k] = nt[t0 + tx * 2 + k]; ctv[k] = ct[t0 + tx * 2 + k]; }

    float s1loc[4] = {0.f, 0.f, 0.f, 0.f};
    float eloc[4]  = {0.f, 0.f, 0.f, 0.f};
    #pragma unroll
    for (int i = 0; i < 4; ++i) {
        float w1v[2], w2v[2];
        #pragma unroll
        for (int k = 0; k < 2; ++k) {
            float d2 = Q2F * (nmv[i] + ntv[k] - 2.f * g1[i][k]);
            float xd = sqrtf(fmaxf(d2, 0.f));
            float e  = K0E * __expf(-xd);
            float dv = QF * (g2[i][k] - ctv[k]);
            float w1 = e * dv;
            float w2 = e * (1.f + xd);
            w1v[k] = w1; w2v[k] = w2;
            s1loc[i] += w1;
            eloc[i]  = fmaf(w2, dv, eloc[i]);
        }
        *(float2*)&W1[(m0 + ty * 4 + i) * TT + t0 + tx * 2] = make_float2(w1v[0], w1v[1]);
        *(float2*)&W2[(m0 + ty * 4 + i) * TT + t0 + tx * 2] = make_float2(w2v[0], w2v[1]);
    }
    #pragma unroll
    for (int off = 16; off >= 1; off >>= 1) {
        #pragma unroll
        for (int i = 0; i < 4; ++i) {
            s1loc[i] += __shfl_xor(s1loc[i], off);
            eloc[i]  += __shfl_xor(eloc[i], off);
        }
    }
    if (tx == 0) {
        #pragma unroll
        for (int i = 0; i < 4; ++i) {
            atomicAdd(&s1g[m0 + ty * 4 + i], s1loc[i]);
            atomicAdd(&Eg[m0 + ty * 4 + i], eloc[i]);
        }
    }
}

// ---------- K3: phase B partial GEMM, no atomics ----------
// grid (KCH=8, m-tiles=8, d-sections=4); block 256 thr (224 active).
// block: P[c][m0:16][d0:56] = sum_{t in chunk} W[m,t] * X[t,d]
__global__ __launch_bounds__(256) void k3_partial(
        const float* __restrict__ W1, const float* __restrict__ W2,
        const float* __restrict__ trp, const float* __restrict__ jxp,
        float* __restrict__ P1, float* __restrict__ P2) {
    __shared__ __align__(16) float Wl1[16][KLEN];
    __shared__ __align__(16) float Wl2[16][KLEN];
    int tid = threadIdx.x;
    int c  = blockIdx.x;      // K chunk
    int mt = blockIdx.y;      // m tile
    int ds = blockIdx.z;      // d section
    int t0 = c * KLEN, m0 = mt * 16;

    // cooperative W tile load: 16 x 512 = 2048 float4 per array
    for (int i = tid; i < 2048; i += 256) {
        int row = i >> 7;            // 128 f4 per row
        int col = (i & 127) << 2;
        *(float4*)&Wl1[row][col] = *(const float4*)&W1[(m0 + row) * TT + t0 + col];
        *(float4*)&Wl2[row][col] = *(const float4*)&W2[(m0 + row) * TT + t0 + col];
    }
    __syncthreads();
    if (tid >= 224) return;

    int dq = tid % 14, mloc = tid / 14;
    int d0 = ds * 56 + dq * 4;

    float4 a1 = {0.f, 0.f, 0.f, 0.f};
    float4 a2 = {0.f, 0.f, 0.f, 0.f};
    for (int t = 0; t < KLEN; t += 4) {
        float4 w1 = *(const float4*)&Wl1[mloc][t];
        float4 w2 = *(const float4*)&Wl2[mloc][t];
        float w1a[4] = {w1.x, w1.y, w1.z, w1.w};
        float w2a[4] = {w2.x, w2.y, w2.z, w2.w};
        #pragma unroll
        for (int tt = 0; tt < 4; ++tt) {
            int rbase = (t0 + t + tt) * DP + d0;
            float4 x1 = *(const float4*)&trp[rbase];
            float4 x2 = *(const float4*)&jxp[rbase];
            a1.x = fmaf(w1a[tt], x1.x, a1.x);
            a1.y = fmaf(w1a[tt], x1.y, a1.y);
            a1.z = fmaf(w1a[tt], x1.z, a1.z);
            a1.w = fmaf(w1a[tt], x1.w, a1.w);
            a2.x = fmaf(w2a[tt], x2.x, a2.x);
            a2.y = fmaf(w2a[tt], x2.y, a2.y);
            a2.z = fmaf(w2a[tt], x2.z, a2.z);
            a2.w = fmaf(w2a[tt], x2.w, a2.w);
        }
    }
    int m = m0 + mloc;
    *(float4*)&P1[((size_t)c * MM + m) * DP + d0] = a1;
    *(float4*)&P2[((size_t)c * MM + m) * DP + d0] = a2;
}

// ---------- K4: chunk-reduce + final forces + energies ----------
__global__ __launch_bounds__(256) void k4_final(
        const float* __restrict__ Rs, const float* __restrict__ xsp,
        const float* __restrict__ P1, const float* __restrict__ P2,
        const float* __restrict__ s1g, const float* __restrict__ Eg,
        float* __restrict__ out) {
    int m = blockIdx.x, tid = threadIdx.x;
    __shared__ float fxs[DD];
    __shared__ float Rl[64];
    if (tid < NA * 3) Rl[tid] = Rs[m * NA * 3 + tid];
    float s1v = s1g[m];
    if (tid < DD) {
        float pa = 0.f, pb = 0.f;
        #pragma unroll
        for (int cc = 0; cc < KCH; ++cc) {
            pa += P1[((size_t)cc * MM + m) * DP + tid];
            pb += P2[((size_t)cc * MM + m) * DP + tid];
        }
        fxs[tid] = QF * xsp[m * DP + tid] * s1v - QF * pa - pb;
    }
    __syncthreads();
    if (tid < NA * 3) {
        int b = tid / 3, c = tid - b * 3;
        float acc = 0.f;
        #pragma unroll
        for (int a = 0; a < NA; ++a) {
            if (a == b) continue;
            int hi = a > b ? a : b, lo = a > b ? b : a;
            int d = hi * (hi - 1) / 2 + lo;
            float dx = Rl[a * 3 + 0] - Rl[b * 3 + 0];
            float dy = Rl[a * 3 + 1] - Rl[b * 3 + 1];
            float dz = Rl[a * 3 + 2] - Rl[b * 3 + 2];
            float r2 = dx * dx + dy * dy + dz * dz;
            float ir = 1.0f / sqrtf(r2);
            float w = fxs[d] * ir * ir * ir;
            float comp = (c == 0) ? dx : ((c == 1) ? dy : dz);
            acc = fmaf(w, comp, acc);
        }
        out[MM + m * NA * 3 + tid] = acc;
    }
    if (tid == 64) out[m] = Eg[m] * INVQ;
}

extern "C" void kernel_launch(void* const* d_in, const int* in_sizes, int n_in,
                              void* d_out, int out_size, void* d_ws, size_t ws_size,
                              hipStream_t stream) {
    const float* Rs = (const float*)d_in[0];
    const float* tr = (const float*)d_in[1];
    const float* jx = (const float*)d_in[2];
    float* out = (float*)d_out;
    float* ws = (float*)d_ws;

    float* trp = ws + OFF_TRP;
    float* jxp = ws + OFF_JXP;
    float* W1  = ws + OFF_W1;
    float* W2  = ws + OFF_W2;
    float* xsp = ws + OFF_XSP;
    float* nt  = ws + OFF_NT;
    float* ct  = ws + OFF_CT;
    float* nm  = ws + OFF_NM;
    float* s1  = ws + OFF_S1;
    float* Eg  = ws + OFF_E;
    float* P1  = ws + OFF_P1;
    float* P2  = ws + OFF_P2;

    k0_fused<<<TT + MM + 1, 256, 0, stream>>>(tr, jx, Rs, trp, jxp, nt, ct, xsp, nm, ws + OFF_S1);
    k2_phaseA<<<dim3(TT / BT, MM / BM), 256, 0, stream>>>(xsp, trp, jxp, nm, nt, ct, W1, W2, s1, Eg);
    k3_partial<<<dim3(KCH, MM / 16, 4), 256, 0, stream>>>(W1, W2, trp, jxp, P1, P2);
    k4_final<<<MM, 256, 0, stream>>>(Rs, xsp, P1, P2, s1, Eg, out);
}

// Round 5
// 79.473 us; speedup vs baseline: 1.4597x; 1.2362x over previous
//
#include <hip/hip_runtime.h>
#include <hip/hip_bf16.h>

#define MM 128      // molecules
#define NA 21       // atoms
#define DD 210      // descriptors
#define DP 224      // padded descriptors (multiple of 32)
#define TT 4096     // training points
#define KCH 16      // K-chunks for phase B partials
#define KLEN 256    // TT / KCH
#define WPAD 4      // LDS W-tile stride pad: (256+4)%32=4 -> conflict-free rows

#define QF   0.22360679774997896f   // sqrt(5)/10
#define Q2F  0.05f                  // Q^2 = 5/100
#define K0E  0.016666666666666666f  // 5/(3*SIG^2) = 1/60
#define INVQ 4.47213595499958f      // 1/Q

// ---- workspace layout (float offsets) ----
#define OFF_TRP 0                       // [TT][DP]
#define OFF_JXP (OFF_TRP + TT*DP)       // [TT][DP]
#define OFF_W1  (OFF_JXP + TT*DP)       // [MM][TT]
#define OFF_W2  (OFF_W1 + MM*TT)        // [MM][TT]
#define OFF_XSP (OFF_W2 + MM*TT)        // [MM][DP]
#define OFF_NT  (OFF_XSP + MM*DP)       // [TT]
#define OFF_CT  (OFF_NT + TT)           // [TT]
#define OFF_NM  (OFF_CT + TT)           // [MM]
#define OFF_S1  (OFF_NM + MM)           // [MM]  (zeroed by k0 tail block)
#define OFF_E   (OFF_S1 + MM)           // [MM]  (zeroed by k0 tail block)
#define OFF_P1  (OFF_E + MM)            // [KCH][MM][DP]
#define OFF_P2  (OFF_P1 + KCH*MM*DP)    // [KCH][MM][DP]
// total = 3,838,336 floats = 15.4 MB

// ---------- K0 hybrid: [0,TT) pad+nt/ct | [TT,TT+MM) descriptors | 1 zero block ----------
__global__ __launch_bounds__(256) void k0_fused(
        const float* __restrict__ tr, const float* __restrict__ jx,
        const float* __restrict__ Rs,
        float* __restrict__ trp, float* __restrict__ jxp,
        float* __restrict__ nt, float* __restrict__ ct,
        float* __restrict__ xsp, float* __restrict__ nmg,
        float* __restrict__ zbase) {
    int b = blockIdx.x, tid = threadIdx.x;
    __shared__ float red0[4], red1[4];
    __shared__ float Rl[64];

    if (b < TT) {
        int t = b;
        float v1 = 0.f, v2 = 0.f;
        if (tid < DD) { v1 = tr[t * DD + tid]; v2 = jx[t * DD + tid]; }
        if (tid < DP) { trp[t * DP + tid] = v1; jxp[t * DP + tid] = v2; }
        float sn = v1 * v1, sc = v1 * v2;
        #pragma unroll
        for (int off = 32; off >= 1; off >>= 1) {
            sn += __shfl_xor(sn, off);
            sc += __shfl_xor(sc, off);
        }
        if ((tid & 63) == 0) { red0[tid >> 6] = sn; red1[tid >> 6] = sc; }
        __syncthreads();
        if (tid == 0) {
            nt[t] = red0[0] + red0[1] + red0[2] + red0[3];
            ct[t] = red1[0] + red1[1] + red1[2] + red1[3];
        }
    } else if (b < TT + MM) {
        int m = b - TT;
        if (tid < NA * 3) Rl[tid] = Rs[m * NA * 3 + tid];
        __syncthreads();
        float v = 0.f;
        if (tid < DP) {
            float x = 0.f;
            if (tid < DD) {
                int d = tid;
                int a = (int)((1.0f + sqrtf(8.0f * (float)d + 1.0f)) * 0.5f);
                while (a * (a - 1) / 2 > d) --a;
                while ((a + 1) * a / 2 <= d) ++a;
                int bb = d - a * (a - 1) / 2;
                float dx = Rl[a * 3 + 0] - Rl[bb * 3 + 0];
                float dy = Rl[a * 3 + 1] - Rl[bb * 3 + 1];
                float dz = Rl[a * 3 + 2] - Rl[bb * 3 + 2];
                x = 1.0f / sqrtf(dx * dx + dy * dy + dz * dz);
            }
            xsp[m * DP + tid] = x;
            v = x * x;
        }
        #pragma unroll
        for (int off = 32; off >= 1; off >>= 1) v += __shfl_xor(v, off);
        if ((tid & 63) == 0) red0[tid >> 6] = v;
        __syncthreads();
        if (tid == 0) nmg[m] = red0[0] + red0[1] + red0[2] + red0[3];
    } else {
        zbase[tid] = 0.f;   // s1 (128) + E (128), contiguous
    }
}

// ---------- K2: phase A -- G1/G2 tiles -> W1,W2, s1, E ----------
// tile: BM=32 x BT=64, BD=32 k-chunk, 256 threads, micro 4m x 2t
#define BM 32
#define BT 64
#define BD 32
#define TS_STR 70   // Ts/Js LDS stride (2-way max on staging stores, b64-aligned reads)
__global__ __launch_bounds__(256) void k2_phaseA(
        const float* __restrict__ xsp, const float* __restrict__ trp,
        const float* __restrict__ jxp, const float* __restrict__ nm,
        const float* __restrict__ nt, const float* __restrict__ ct,
        float* __restrict__ W1, float* __restrict__ W2,
        float* __restrict__ s1g, float* __restrict__ Eg) {
    __shared__ __align__(16) float As[BD][BM + 4];     // stride 36 (16B-aligned rows)
    __shared__ __align__(16) float Ts[BD][TS_STR];
    __shared__ __align__(16) float Js[BD][TS_STR];
    int tid = threadIdx.x;
    int t0 = blockIdx.x * BT;
    int m0 = blockIdx.y * BM;
    int ty = tid >> 5;      // 0..7  -> m group (4 m each)
    int tx = tid & 31;      // 0..31 -> t pair (2 t each)
    float g1[4][2] = {{0.f}};
    float g2[4][2] = {{0.f}};
    int amm = tid >> 3;     // 0..31 m row for A staging
    int aseg = tid & 7;     // 0..7  -> 4 d's
    int ttt = tid >> 2;     // 0..63 t row for T/J staging
    int tseg = tid & 3;     // 0..3  -> 8 d's

    for (int dk = 0; dk < DP; dk += BD) {
        float4 av = *(const float4*)(xsp + (m0 + amm) * DP + dk + aseg * 4);
        const float* tp = trp + (t0 + ttt) * DP + dk + tseg * 8;
        const float* jp = jxp + (t0 + ttt) * DP + dk + tseg * 8;
        float4 tv0 = *(const float4*)(tp);
        float4 tv1 = *(const float4*)(tp + 4);
        float4 jv0 = *(const float4*)(jp);
        float4 jv1 = *(const float4*)(jp + 4);
        __syncthreads();
        As[aseg * 4 + 0][amm] = av.x; As[aseg * 4 + 1][amm] = av.y;
        As[aseg * 4 + 2][amm] = av.z; As[aseg * 4 + 3][amm] = av.w;
        int c0 = tseg * 8;
        Ts[c0 + 0][ttt] = tv0.x; Ts[c0 + 1][ttt] = tv0.y; Ts[c0 + 2][ttt] = tv0.z; Ts[c0 + 3][ttt] = tv0.w;
        Ts[c0 + 4][ttt] = tv1.x; Ts[c0 + 5][ttt] = tv1.y; Ts[c0 + 6][ttt] = tv1.z; Ts[c0 + 7][ttt] = tv1.w;
        Js[c0 + 0][ttt] = jv0.x; Js[c0 + 1][ttt] = jv0.y; Js[c0 + 2][ttt] = jv0.z; Js[c0 + 3][ttt] = jv0.w;
        Js[c0 + 4][ttt] = jv1.x; Js[c0 + 5][ttt] = jv1.y; Js[c0 + 6][ttt] = jv1.z; Js[c0 + 7][ttt] = jv1.w;
        __syncthreads();
        #pragma unroll
        for (int dd = 0; dd < BD; ++dd) {
            float4 a  = *(const float4*)&As[dd][ty * 4];
            float2 tv = *(const float2*)&Ts[dd][tx * 2];
            float2 jv = *(const float2*)&Js[dd][tx * 2];
            float am[4] = {a.x, a.y, a.z, a.w};
            float t2[2] = {tv.x, tv.y};
            float j2[2] = {jv.x, jv.y};
            #pragma unroll
            for (int i = 0; i < 4; ++i) {
                #pragma unroll
                for (int k = 0; k < 2; ++k) {
                    g1[i][k] = fmaf(am[i], t2[k], g1[i][k]);
                    g2[i][k] = fmaf(am[i], j2[k], g2[i][k]);
                }
            }
        }
    }

    float nmv[4], ntv[2], ctv[2];
    #pragma unroll
    for (int i = 0; i < 4; ++i) nmv[i] = nm[m0 + ty * 4 + i];
    #pragma unroll
    for (int k = 0; k < 2; ++k) { ntv[k] = nt[t0 + tx * 2 + k]; ctv[k] = ct[t0 + tx * 2 + k]; }

    float s1loc[4] = {0.f, 0.f, 0.f, 0.f};
    float eloc[4]  = {0.f, 0.f, 0.f, 0.f};
    #pragma unroll
    for (int i = 0; i < 4; ++i) {
        float w1v[2], w2v[2];
        #pragma unroll
        for (int k = 0; k < 2; ++k) {
            float d2 = Q2F * (nmv[i] + ntv[k] - 2.f * g1[i][k]);
            float xd = sqrtf(fmaxf(d2, 0.f));
            float e  = K0E * __expf(-xd);
            float dv = QF * (g2[i][k] - ctv[k]);
            float w1 = e * dv;
            float w2 = e * (1.f + xd);
            w1v[k] = w1; w2v[k] = w2;
            s1loc[i] += w1;
            eloc[i]  = fmaf(w2, dv, eloc[i]);
        }
        *(float2*)&W1[(m0 + ty * 4 + i) * TT + t0 + tx * 2] = make_float2(w1v[0], w1v[1]);
        *(float2*)&W2[(m0 + ty * 4 + i) * TT + t0 + tx * 2] = make_float2(w2v[0], w2v[1]);
    }
    #pragma unroll
    for (int off = 16; off >= 1; off >>= 1) {
        #pragma unroll
        for (int i = 0; i < 4; ++i) {
            s1loc[i] += __shfl_xor(s1loc[i], off);
            eloc[i]  += __shfl_xor(eloc[i], off);
        }
    }
    if (tx == 0) {
        #pragma unroll
        for (int i = 0; i < 4; ++i) {
            atomicAdd(&s1g[m0 + ty * 4 + i], s1loc[i]);
            atomicAdd(&Eg[m0 + ty * 4 + i], eloc[i]);
        }
    }
}

// ---------- K3 v3: phase B partial GEMM, no atomics, high occupancy ----------
// grid (KCH=16, m-tiles=8, d-sections=4) = 512 blocks; 33 KB LDS -> 4 blocks/CU.
// block: P[c][m0:16][d0:56] = sum_{t in chunk} W[m,t] * X[t,d]
__global__ __launch_bounds__(256) void k3_partial(
        const float* __restrict__ W1, const float* __restrict__ W2,
        const float* __restrict__ trp, const float* __restrict__ jxp,
        float* __restrict__ P1, float* __restrict__ P2) {
    __shared__ __align__(16) float Wl1[16][KLEN + WPAD];
    __shared__ __align__(16) float Wl2[16][KLEN + WPAD];
    int tid = threadIdx.x;
    int c  = blockIdx.x;      // K chunk
    int mt = blockIdx.y;      // m tile
    int ds = blockIdx.z;      // d section
    int t0 = c * KLEN, m0 = mt * 16;

    // cooperative W tile load: 16 x 256 = 1024 float4 per array
    for (int i = tid; i < 1024; i += 256) {
        int row = i >> 6;            // 64 f4 per row
        int col = (i & 63) << 2;
        *(float4*)&Wl1[row][col] = *(const float4*)&W1[(m0 + row) * TT + t0 + col];
        *(float4*)&Wl2[row][col] = *(const float4*)&W2[(m0 + row) * TT + t0 + col];
    }
    __syncthreads();
    if (tid >= 224) return;

    int dq = tid % 14, mloc = tid / 14;
    int d0 = ds * 56 + dq * 4;

    float4 a1 = {0.f, 0.f, 0.f, 0.f};
    float4 a2 = {0.f, 0.f, 0.f, 0.f};
    for (int t = 0; t < KLEN; t += 8) {
        float4 x1[8], x2[8];
        #pragma unroll
        for (int tt = 0; tt < 8; ++tt) {
            int rbase = (t0 + t + tt) * DP + d0;
            x1[tt] = *(const float4*)&trp[rbase];
            x2[tt] = *(const float4*)&jxp[rbase];
        }
        float4 wA1 = *(const float4*)&Wl1[mloc][t];
        float4 wB1 = *(const float4*)&Wl1[mloc][t + 4];
        float4 wA2 = *(const float4*)&Wl2[mloc][t];
        float4 wB2 = *(const float4*)&Wl2[mloc][t + 4];
        float w1a[8] = {wA1.x, wA1.y, wA1.z, wA1.w, wB1.x, wB1.y, wB1.z, wB1.w};
        float w2a[8] = {wA2.x, wA2.y, wA2.z, wA2.w, wB2.x, wB2.y, wB2.z, wB2.w};
        #pragma unroll
        for (int tt = 0; tt < 8; ++tt) {
            a1.x = fmaf(w1a[tt], x1[tt].x, a1.x);
            a1.y = fmaf(w1a[tt], x1[tt].y, a1.y);
            a1.z = fmaf(w1a[tt], x1[tt].z, a1.z);
            a1.w = fmaf(w1a[tt], x1[tt].w, a1.w);
            a2.x = fmaf(w2a[tt], x2[tt].x, a2.x);
            a2.y = fmaf(w2a[tt], x2[tt].y, a2.y);
            a2.z = fmaf(w2a[tt], x2[tt].z, a2.z);
            a2.w = fmaf(w2a[tt], x2[tt].w, a2.w);
        }
    }
    int m = m0 + mloc;
    *(float4*)&P1[((size_t)c * MM + m) * DP + d0] = a1;
    *(float4*)&P2[((size_t)c * MM + m) * DP + d0] = a2;
}

// ---------- K4: chunk-reduce + final forces + energies ----------
__global__ __launch_bounds__(256) void k4_final(
        const float* __restrict__ Rs, const float* __restrict__ xsp,
        const float* __restrict__ P1, const float* __restrict__ P2,
        const float* __restrict__ s1g, const float* __restrict__ Eg,
        float* __restrict__ out) {
    int m = blockIdx.x, tid = threadIdx.x;
    __shared__ float fxs[DD];
    __shared__ float Rl[64];
    if (tid < NA * 3) Rl[tid] = Rs[m * NA * 3 + tid];
    float s1v = s1g[m];
    if (tid < DD) {
        float pa = 0.f, pb = 0.f;
        #pragma unroll
        for (int cc = 0; cc < KCH; ++cc) {
            pa += P1[((size_t)cc * MM + m) * DP + tid];
            pb += P2[((size_t)cc * MM + m) * DP + tid];
        }
        fxs[tid] = QF * xsp[m * DP + tid] * s1v - QF * pa - pb;
    }
    __syncthreads();
    if (tid < NA * 3) {
        int b = tid / 3, c = tid - b * 3;
        float acc = 0.f;
        #pragma unroll
        for (int a = 0; a < NA; ++a) {
            if (a == b) continue;
            int hi = a > b ? a : b, lo = a > b ? b : a;
            int d = hi * (hi - 1) / 2 + lo;
            float dx = Rl[a * 3 + 0] - Rl[b * 3 + 0];
            float dy = Rl[a * 3 + 1] - Rl[b * 3 + 1];
            float dz = Rl[a * 3 + 2] - Rl[b * 3 + 2];
            float r2 = dx * dx + dy * dy + dz * dz;
            float ir = 1.0f / sqrtf(r2);
            float w = fxs[d] * ir * ir * ir;
            float comp = (c == 0) ? dx : ((c == 1) ? dy : dz);
            acc = fmaf(w, comp, acc);
        }
        out[MM + m * NA * 3 + tid] = acc;
    }
    if (tid == 64) out[m] = Eg[m] * INVQ;
}

extern "C" void kernel_launch(void* const* d_in, const int* in_sizes, int n_in,
                              void* d_out, int out_size, void* d_ws, size_t ws_size,
                              hipStream_t stream) {
    const float* Rs = (const float*)d_in[0];
    const float* tr = (const float*)d_in[1];
    const float* jx = (const float*)d_in[2];
    float* out = (float*)d_out;
    float* ws = (float*)d_ws;

    float* trp = ws + OFF_TRP;
    float* jxp = ws + OFF_JXP;
    float* W1  = ws + OFF_W1;
    float* W2  = ws + OFF_W2;
    float* xsp = ws + OFF_XSP;
    float* nt  = ws + OFF_NT;
    float* ct  = ws + OFF_CT;
    float* nm  = ws + OFF_NM;
    float* s1  = ws + OFF_S1;
    float* Eg  = ws + OFF_E;
    float* P1  = ws + OFF_P1;
    float* P2  = ws + OFF_P2;

    k0_fused<<<TT + MM + 1, 256, 0, stream>>>(tr, jx, Rs, trp, jxp, nt, ct, xsp, nm, ws + OFF_S1);
    k2_phaseA<<<dim3(TT / BT, MM / BM), 256, 0, stream>>>(xsp, trp, jxp, nm, nt, ct, W1, W2, s1, Eg);
    k3_partial<<<dim3(KCH, MM / 16, 4), 256, 0, stream>>>(W1, W2, trp, jxp, P1, P2);
    k4_final<<<MM, 256, 0, stream>>>(Rs, xsp, P1, P2, s1, Eg, out);
}

// Round 6
// 70.828 us; speedup vs baseline: 1.6379x; 1.1221x over previous
//
#include <hip/hip_runtime.h>
#include <hip/hip_bf16.h>

#define MM 128      // molecules
#define NA 21       // atoms
#define DD 210      // descriptors
#define DP 224      // padded descriptors
#define TT 4096     // training points
#define NC 64       // t-chunks
#define CHT 64      // t per chunk
#define XPAD 20     // xst LDS row stride (floats): keeps float4 alignment

#define QF   0.22360679774997896f   // sqrt(5)/10
#define Q2F  0.05f                  // Q^2
#define K0E  0.016666666666666666f  // 5/(3*SIG^2)
#define INVQ 4.47213595499958f      // 1/Q

// ---- workspace layout (float offsets) ----
#define OFF_TRP  0                        // [TT][DP]
#define OFF_JXP  (OFF_TRP + TT*DP)        // [TT][DP]
#define OFF_TRPT (OFF_JXP + TT*DP)        // [DP][TT]
#define OFF_JXPT (OFF_TRPT + DP*TT)       // [DP][TT]
#define OFF_XSP  (OFF_JXPT + DP*TT)       // [MM][DP]
#define OFF_NT   (OFF_XSP + MM*DP)        // [TT]
#define OFF_CT   (OFF_NT + TT)            // [TT]
#define OFF_NM   (OFF_CT + TT)            // [MM]
#define OFF_S1P  (OFF_NM + MM)            // [NC][MM]
#define OFF_EP   (OFF_S1P + NC*MM)        // [NC][MM]
#define OFF_P1   (OFF_EP + NC*MM)         // [NC][MM][DP]
#define OFF_P2   (OFF_P1 + NC*MM*DP)      // [NC][MM][DP]
// total ~7.4M floats = 29.6 MB

// ---------- K0: blocks [0,128): 32-t tiles -> trp/jxp + trpT/jxpT + nt/ct
// ----------     blocks [128,256): per-molecule descriptors xs + nm ----------
__global__ __launch_bounds__(256) void k0_prep(
        const float* __restrict__ tr, const float* __restrict__ jx,
        const float* __restrict__ Rs,
        float* __restrict__ trp, float* __restrict__ jxp,
        float* __restrict__ trpT, float* __restrict__ jxpT,
        float* __restrict__ nt, float* __restrict__ ct,
        float* __restrict__ xsp, float* __restrict__ nmg) {
    __shared__ float S1[32][225];
    __shared__ float S2[32][225];
    int b = blockIdx.x, tid = threadIdx.x;

    if (b < 128) {
        int t0 = b * 32;
        for (int i = tid; i < 32 * 224; i += 256) {
            int t = i / 224, d = i - t * 224;
            float v1 = 0.f, v2 = 0.f;
            if (d < DD) { v1 = tr[(t0 + t) * DD + d]; v2 = jx[(t0 + t) * DD + d]; }
            S1[t][d] = v1; S2[t][d] = v2;
            trp[(t0 + t) * DP + d] = v1;
            jxp[(t0 + t) * DP + d] = v2;
        }
        __syncthreads();
        if (tid < 64) {   // nt/ct: 2 threads per t, halves of d-range
            int t = tid & 31, h = tid >> 5;
            float sn = 0.f, sc = 0.f;
            int d0 = h * 112;
            for (int d = d0; d < d0 + 112; ++d) {
                float v1 = S1[t][d];
                sn = fmaf(v1, v1, sn);
                sc = fmaf(v1, S2[t][d], sc);
            }
            sn += __shfl_xor(sn, 32);
            sc += __shfl_xor(sc, 32);
            if (h == 0) { nt[t0 + t] = sn; ct[t0 + t] = sc; }
        }
        // transposed writes (coalesced 128B segments per d)
        for (int i = tid; i < 224 * 32; i += 256) {
            int d = i >> 5, t = i & 31;
            trpT[d * TT + t0 + t] = S1[t][d];
            jxpT[d * TT + t0 + t] = S2[t][d];
        }
    } else {
        int m = b - 128;
        float* Rl  = &S1[0][0];
        float* red = &S2[0][0];
        if (tid < NA * 3) Rl[tid] = Rs[m * NA * 3 + tid];
        __syncthreads();
        float v = 0.f;
        if (tid < DP) {
            float x = 0.f;
            if (tid < DD) {
                int d = tid;
                int a = (int)((1.0f + sqrtf(8.0f * (float)d + 1.0f)) * 0.5f);
                while (a * (a - 1) / 2 > d) --a;
                while ((a + 1) * a / 2 <= d) ++a;
                int bb = d - a * (a - 1) / 2;
                float dx = Rl[a * 3 + 0] - Rl[bb * 3 + 0];
                float dy = Rl[a * 3 + 1] - Rl[bb * 3 + 1];
                float dz = Rl[a * 3 + 2] - Rl[bb * 3 + 2];
                x = 1.0f / sqrtf(dx * dx + dy * dy + dz * dz);
            }
            xsp[m * DP + tid] = x;
            v = x * x;
        }
        #pragma unroll
        for (int off = 32; off >= 1; off >>= 1) v += __shfl_xor(v, off);
        if ((tid & 63) == 0) red[tid >> 6] = v;
        __syncthreads();
        if (tid == 0) nmg[m] = red[0] + red[1] + red[2] + red[3];
    }
}

// ---------- K23: fused phase A (G->W in LDS) + phase B (A-partials) ----------
// grid (NC=64 t-chunks, MM/16=8 m-tiles), 256 thr (4 waves).
// Phase A: wave my owns m-quad {my*4..+3} x all 64 t (tx=lane). K-loop over 224,
//   reads X^T rows coalesced + xs^T LDS broadcast. No barriers in loop.
// Phase B: thread d accumulates A1/A2[16 m][d] over the 64-t chunk, W from LDS.
__global__ __launch_bounds__(256) void k23_fused(
        const float* __restrict__ trp, const float* __restrict__ jxp,
        const float* __restrict__ trpT, const float* __restrict__ jxpT,
        const float* __restrict__ xsp, const float* __restrict__ nt,
        const float* __restrict__ ct, const float* __restrict__ nm,
        float* __restrict__ S1P, float* __restrict__ EP,
        float* __restrict__ P1, float* __restrict__ P2) {
    __shared__ __align__(16) float xst[224 * XPAD];   // [k][m], pad 20
    __shared__ __align__(16) float Wl1[16][CHT];
    __shared__ __align__(16) float Wl2[16][CHT];
    int tid = threadIdx.x;
    int c = blockIdx.x, m0 = blockIdx.y * 16;
    int t0 = c * CHT;
    int tx = tid & 63, my = tid >> 6, my4 = my * 4;

    // stage xs^T tile: [16 m][224 k] -> xst[k][m]
    for (int i = tid; i < 16 * 224; i += 256) {
        int m = i / 224, k = i - m * 224;
        xst[k * XPAD + m] = xsp[(m0 + m) * DP + k];
    }
    __syncthreads();

    // ---- phase A: G1/G2 register GEMM ----
    float g1[4] = {0.f, 0.f, 0.f, 0.f};
    float g2[4] = {0.f, 0.f, 0.f, 0.f};
    const float* tb = trpT + t0 + tx;
    const float* jb = jxpT + t0 + tx;
    for (int k = 0; k < DP; k += 8) {
        float xt[8], jt[8];
        #pragma unroll
        for (int u = 0; u < 8; ++u) {
            xt[u] = tb[(k + u) * TT];
            jt[u] = jb[(k + u) * TT];
        }
        #pragma unroll
        for (int u = 0; u < 8; ++u) {
            float4 a = *(const float4*)&xst[(k + u) * XPAD + my4];
            g1[0] = fmaf(a.x, xt[u], g1[0]);
            g1[1] = fmaf(a.y, xt[u], g1[1]);
            g1[2] = fmaf(a.z, xt[u], g1[2]);
            g1[3] = fmaf(a.w, xt[u], g1[3]);
            g2[0] = fmaf(a.x, jt[u], g2[0]);
            g2[1] = fmaf(a.y, jt[u], g2[1]);
            g2[2] = fmaf(a.z, jt[u], g2[2]);
            g2[3] = fmaf(a.w, jt[u], g2[3]);
        }
    }

    // ---- W epilogue -> LDS, s1/E chunk partials ----
    float ntv = nt[t0 + tx], ctv = ct[t0 + tx];
    float s1l[4], el[4];
    #pragma unroll
    for (int i = 0; i < 4; ++i) {
        float nmv = nm[m0 + my4 + i];
        float d2 = Q2F * (nmv + ntv - 2.f * g1[i]);
        float xd = sqrtf(fmaxf(d2, 0.f));
        float e  = K0E * __expf(-xd);
        float dv = QF * (g2[i] - ctv);
        float w1 = e * dv;
        float w2 = e * (1.f + xd);
        Wl1[my4 + i][tx] = w1;
        Wl2[my4 + i][tx] = w2;
        s1l[i] = w1;
        el[i]  = w2 * dv;
    }
    #pragma unroll
    for (int off = 32; off >= 1; off >>= 1) {
        #pragma unroll
        for (int i = 0; i < 4; ++i) {
            s1l[i] += __shfl_xor(s1l[i], off);
            el[i]  += __shfl_xor(el[i], off);
        }
    }
    if (tx == 0) {
        #pragma unroll
        for (int i = 0; i < 4; ++i) {
            S1P[c * MM + m0 + my4 + i] = s1l[i];
            EP [c * MM + m0 + my4 + i] = el[i];
        }
    }
    __syncthreads();

    // ---- phase B: A-partials over this chunk ----
    if (tid < DP) {
        float a1[16], a2[16];
        #pragma unroll
        for (int m = 0; m < 16; ++m) { a1[m] = 0.f; a2[m] = 0.f; }
        for (int t4 = 0; t4 < CHT; t4 += 4) {
            float x1[4], x2[4];
            #pragma unroll
            for (int u = 0; u < 4; ++u) {
                x1[u] = trp[(t0 + t4 + u) * DP + tid];
                x2[u] = jxp[(t0 + t4 + u) * DP + tid];
            }
            #pragma unroll
            for (int m = 0; m < 16; ++m) {
                float4 w1 = *(const float4*)&Wl1[m][t4];
                float4 w2 = *(const float4*)&Wl2[m][t4];
                a1[m] = fmaf(w1.x, x1[0], fmaf(w1.y, x1[1], fmaf(w1.z, x1[2], fmaf(w1.w, x1[3], a1[m]))));
                a2[m] = fmaf(w2.x, x2[0], fmaf(w2.y, x2[1], fmaf(w2.z, x2[2], fmaf(w2.w, x2[3], a2[m]))));
            }
        }
        #pragma unroll
        for (int m = 0; m < 16; ++m) {
            P1[(c * MM + m0 + m) * DP + tid] = a1[m];
            P2[(c * MM + m0 + m) * DP + tid] = a2[m];
        }
    }
}

// ---------- K4: chunk-reduce + final forces + energies ----------
__global__ __launch_bounds__(256) void k4_final(
        const float* __restrict__ Rs, const float* __restrict__ xsp,
        const float* __restrict__ P1, const float* __restrict__ P2,
        const float* __restrict__ S1P, const float* __restrict__ EP,
        float* __restrict__ out) {
    int m = blockIdx.x, tid = threadIdx.x;
    __shared__ float fxs[DD];
    __shared__ float Rl[64];
    __shared__ float sE[2];
    if (tid < NA * 3) Rl[tid] = Rs[m * NA * 3 + tid];
    if (tid >= 64 && tid < 128) {      // wave 1: reduce s1/E over 64 chunks
        int cc = tid - 64;
        float s = S1P[cc * MM + m];
        float e = EP [cc * MM + m];
        #pragma unroll
        for (int off = 32; off >= 1; off >>= 1) {
            s += __shfl_xor(s, off);
            e += __shfl_xor(e, off);
        }
        if (cc == 0) { sE[0] = s; sE[1] = e; }
    }
    float pa = 0.f, pb = 0.f;
    if (tid < DD) {
        for (int cc = 0; cc < NC; ++cc) {
            pa += P1[(cc * MM + m) * DP + tid];
            pb += P2[(cc * MM + m) * DP + tid];
        }
    }
    __syncthreads();
    if (tid < DD)
        fxs[tid] = QF * xsp[m * DP + tid] * sE[0] - QF * pa - pb;
    __syncthreads();
    if (tid < NA * 3) {
        int b = tid / 3, c = tid - b * 3;
        float acc = 0.f;
        #pragma unroll
        for (int a = 0; a < NA; ++a) {
            if (a == b) continue;
            int hi = a > b ? a : b, lo = a > b ? b : a;
            int d = hi * (hi - 1) / 2 + lo;
            float dx = Rl[a * 3 + 0] - Rl[b * 3 + 0];
            float dy = Rl[a * 3 + 1] - Rl[b * 3 + 1];
            float dz = Rl[a * 3 + 2] - Rl[b * 3 + 2];
            float r2 = dx * dx + dy * dy + dz * dz;
            float ir = 1.0f / sqrtf(r2);
            float w = fxs[d] * ir * ir * ir;
            float comp = (c == 0) ? dx : ((c == 1) ? dy : dz);
            acc = fmaf(w, comp, acc);
        }
        out[MM + m * NA * 3 + tid] = acc;
    }
    if (tid == 0) out[m] = sE[1] * INVQ;
}

extern "C" void kernel_launch(void* const* d_in, const int* in_sizes, int n_in,
                              void* d_out, int out_size, void* d_ws, size_t ws_size,
                              hipStream_t stream) {
    const float* Rs = (const float*)d_in[0];
    const float* tr = (const float*)d_in[1];
    const float* jx = (const float*)d_in[2];
    float* out = (float*)d_out;
    float* ws = (float*)d_ws;

    float* trp  = ws + OFF_TRP;
    float* jxp  = ws + OFF_JXP;
    float* trpT = ws + OFF_TRPT;
    float* jxpT = ws + OFF_JXPT;
    float* xsp  = ws + OFF_XSP;
    float* nt   = ws + OFF_NT;
    float* ct   = ws + OFF_CT;
    float* nm   = ws + OFF_NM;
    float* S1P  = ws + OFF_S1P;
    float* EP   = ws + OFF_EP;
    float* P1   = ws + OFF_P1;
    float* P2   = ws + OFF_P2;

    k0_prep<<<256, 256, 0, stream>>>(tr, jx, Rs, trp, jxp, trpT, jxpT, nt, ct, xsp, nm);
    k23_fused<<<dim3(NC, MM / 16), 256, 0, stream>>>(trp, jxp, trpT, jxpT, xsp, nt, ct, nm, S1P, EP, P1, P2);
    k4_final<<<MM, 256, 0, stream>>>(Rs, xsp, P1, P2, S1P, EP, out);
}

// Round 7
// 68.636 us; speedup vs baseline: 1.6902x; 1.0319x over previous
//
#include <hip/hip_runtime.h>
#include <hip/hip_bf16.h>

#define MM 128      // molecules
#define NA 21       // atoms
#define DD 210      // descriptors
#define DP 224      // padded descriptors
#define TT 4096     // training points
#define NC 64       // t-chunks
#define CHT 64      // t per chunk
#define XPAD 20     // xst LDS row stride (floats): keeps float4 alignment

#define QF   0.22360679774997896f   // sqrt(5)/10
#define Q2F  0.05f                  // Q^2
#define K0E  0.016666666666666666f  // 5/(3*SIG^2)
#define INVQ 4.47213595499958f      // 1/Q

// ---- workspace layout (float offsets) ----
#define OFF_TRP  0                        // [TT][DP]
#define OFF_JXP  (OFF_TRP + TT*DP)        // [TT][DP]
#define OFF_TRPT (OFF_JXP + TT*DP)        // [DP][TT]
#define OFF_JXPT (OFF_TRPT + DP*TT)       // [DP][TT]
#define OFF_XSP  (OFF_JXPT + DP*TT)       // [MM][DP]
#define OFF_NT   (OFF_XSP + MM*DP)        // [TT]
#define OFF_CT   (OFF_NT + TT)            // [TT]
#define OFF_NM   (OFF_CT + TT)            // [MM]
#define OFF_S1P  (OFF_NM + MM)            // [NC][MM]
#define OFF_EP   (OFF_S1P + NC*MM)        // [NC][MM]
#define OFF_P1   (OFF_EP + NC*MM)         // [NC][MM][DP]
#define OFF_P2   (OFF_P1 + NC*MM*DP)      // [NC][MM][DP]

// ---------- K0: blocks [0,128): 32-t tiles -> trp/jxp + trpT/jxpT + nt/ct
// ----------     blocks [128,256): per-molecule descriptors xs + nm ----------
__global__ __launch_bounds__(256) void k0_prep(
        const float* __restrict__ tr, const float* __restrict__ jx,
        const float* __restrict__ Rs,
        float* __restrict__ trp, float* __restrict__ jxp,
        float* __restrict__ trpT, float* __restrict__ jxpT,
        float* __restrict__ nt, float* __restrict__ ct,
        float* __restrict__ xsp, float* __restrict__ nmg) {
    __shared__ float S1[32][225];
    __shared__ float S2[32][225];
    int b = blockIdx.x, tid = threadIdx.x;

    if (b < 128) {
        int t0 = b * 32;
        for (int i = tid; i < 32 * 224; i += 256) {
            int t = i / 224, d = i - t * 224;
            float v1 = 0.f, v2 = 0.f;
            if (d < DD) { v1 = tr[(t0 + t) * DD + d]; v2 = jx[(t0 + t) * DD + d]; }
            S1[t][d] = v1; S2[t][d] = v2;
            trp[(t0 + t) * DP + d] = v1;
            jxp[(t0 + t) * DP + d] = v2;
        }
        __syncthreads();
        if (tid < 64) {   // nt/ct: 2 threads per t, halves of d-range
            int t = tid & 31, h = tid >> 5;
            float sn = 0.f, sc = 0.f;
            int d0 = h * 112;
            for (int d = d0; d < d0 + 112; ++d) {
                float v1 = S1[t][d];
                sn = fmaf(v1, v1, sn);
                sc = fmaf(v1, S2[t][d], sc);
            }
            sn += __shfl_xor(sn, 32);
            sc += __shfl_xor(sc, 32);
            if (h == 0) { nt[t0 + t] = sn; ct[t0 + t] = sc; }
        }
        for (int i = tid; i < 224 * 32; i += 256) {
            int d = i >> 5, t = i & 31;
            trpT[d * TT + t0 + t] = S1[t][d];
            jxpT[d * TT + t0 + t] = S2[t][d];
        }
    } else {
        int m = b - 128;
        float* Rl  = &S1[0][0];
        float* red = &S2[0][0];
        if (tid < NA * 3) Rl[tid] = Rs[m * NA * 3 + tid];
        __syncthreads();
        float v = 0.f;
        if (tid < DP) {
            float x = 0.f;
            if (tid < DD) {
                int d = tid;
                int a = (int)((1.0f + sqrtf(8.0f * (float)d + 1.0f)) * 0.5f);
                while (a * (a - 1) / 2 > d) --a;
                while ((a + 1) * a / 2 <= d) ++a;
                int bb = d - a * (a - 1) / 2;
                float dx = Rl[a * 3 + 0] - Rl[bb * 3 + 0];
                float dy = Rl[a * 3 + 1] - Rl[bb * 3 + 1];
                float dz = Rl[a * 3 + 2] - Rl[bb * 3 + 2];
                x = 1.0f / sqrtf(dx * dx + dy * dy + dz * dz);
            }
            xsp[m * DP + tid] = x;
            v = x * x;
        }
        #pragma unroll
        for (int off = 32; off >= 1; off >>= 1) v += __shfl_xor(v, off);
        if ((tid & 63) == 0) red[tid >> 6] = v;
        __syncthreads();
        if (tid == 0) nmg[m] = red[0] + red[1] + red[2] + red[3];
    }
}

// ---------- K23: fused phase A (G->W in LDS) + phase B, software-pipelined ----------
#define PA_LOAD(bt, bj, KK) do { \
    _Pragma("unroll") \
    for (int u = 0; u < 8; ++u) { \
        bt[u] = tb[(KK + u) * TT]; \
        bj[u] = jb[(KK + u) * TT]; \
    } \
} while (0)

#define PA_FMA(bt, bj, KK) do { \
    _Pragma("unroll") \
    for (int u = 0; u < 8; ++u) { \
        float4 a = *(const float4*)&xst[(KK + u) * XPAD + my4]; \
        g1[0] = fmaf(a.x, bt[u], g1[0]); \
        g1[1] = fmaf(a.y, bt[u], g1[1]); \
        g1[2] = fmaf(a.z, bt[u], g1[2]); \
        g1[3] = fmaf(a.w, bt[u], g1[3]); \
        g2[0] = fmaf(a.x, bj[u], g2[0]); \
        g2[1] = fmaf(a.y, bj[u], g2[1]); \
        g2[2] = fmaf(a.z, bj[u], g2[2]); \
        g2[3] = fmaf(a.w, bj[u], g2[3]); \
    } \
} while (0)

#define PB_LOAD(xa, xb, T4) do { \
    _Pragma("unroll") \
    for (int u = 0; u < 4; ++u) { \
        xa[u] = trp[(t0 + (T4) + u) * DP + tid]; \
        xb[u] = jxp[(t0 + (T4) + u) * DP + tid]; \
    } \
} while (0)

#define PB_FMA(xa, xb, T4) do { \
    _Pragma("unroll") \
    for (int m = 0; m < 16; ++m) { \
        float4 w1 = *(const float4*)&Wl1[m][(T4)]; \
        float4 w2 = *(const float4*)&Wl2[m][(T4)]; \
        a1[m] = fmaf(w1.x, xa[0], fmaf(w1.y, xa[1], fmaf(w1.z, xa[2], fmaf(w1.w, xa[3], a1[m])))); \
        a2[m] = fmaf(w2.x, xb[0], fmaf(w2.y, xb[1], fmaf(w2.z, xb[2], fmaf(w2.w, xb[3], a2[m])))); \
    } \
} while (0)

__global__ __launch_bounds__(256) void k23_fused(
        const float* __restrict__ trp, const float* __restrict__ jxp,
        const float* __restrict__ trpT, const float* __restrict__ jxpT,
        const float* __restrict__ xsp, const float* __restrict__ nt,
        const float* __restrict__ ct, const float* __restrict__ nm,
        float* __restrict__ S1P, float* __restrict__ EP,
        float* __restrict__ P1, float* __restrict__ P2) {
    __shared__ __align__(16) float xst[224 * XPAD];   // [k][m]
    __shared__ __align__(16) float Wl1[16][CHT];
    __shared__ __align__(16) float Wl2[16][CHT];
    int tid = threadIdx.x;
    int c = blockIdx.x, m0 = blockIdx.y * 16;
    int t0 = c * CHT;
    int tx = tid & 63, my = tid >> 6, my4 = my * 4;

    for (int i = tid; i < 16 * 224; i += 256) {
        int m = i / 224, k = i - m * 224;
        xst[k * XPAD + m] = xsp[(m0 + m) * DP + k];
    }
    __syncthreads();

    // ---- phase A: G1/G2 register GEMM, 2-slab register pipeline ----
    float g1[4] = {0.f, 0.f, 0.f, 0.f};
    float g2[4] = {0.f, 0.f, 0.f, 0.f};
    const float* tb = trpT + t0 + tx;
    const float* jb = jxpT + t0 + tx;
    {
        float p0t[8], p0j[8], p1t[8], p1j[8];
        PA_LOAD(p0t, p0j, 0);
        int k = 0;
        for (; k < DP - 16; k += 16) {          // k = 0..192, 13 iters
            PA_LOAD(p1t, p1j, k + 8);
            PA_FMA(p0t, p0j, k);
            PA_LOAD(p0t, p0j, k + 16);
            PA_FMA(p1t, p1j, k + 8);
        }
        PA_LOAD(p1t, p1j, DP - 8);              // slab 216
        PA_FMA(p0t, p0j, DP - 16);              // 208
        PA_FMA(p1t, p1j, DP - 8);               // 216
    }

    // ---- W epilogue -> LDS, s1/E chunk partials ----
    float ntv = nt[t0 + tx], ctv = ct[t0 + tx];
    float s1l[4], el[4];
    #pragma unroll
    for (int i = 0; i < 4; ++i) {
        float nmv = nm[m0 + my4 + i];
        float d2 = Q2F * (nmv + ntv - 2.f * g1[i]);
        float xd = sqrtf(fmaxf(d2, 0.f));
        float e  = K0E * __expf(-xd);
        float dv = QF * (g2[i] - ctv);
        float w1 = e * dv;
        float w2 = e * (1.f + xd);
        Wl1[my4 + i][tx] = w1;
        Wl2[my4 + i][tx] = w2;
        s1l[i] = w1;
        el[i]  = w2 * dv;
    }
    #pragma unroll
    for (int off = 32; off >= 1; off >>= 1) {
        #pragma unroll
        for (int i = 0; i < 4; ++i) {
            s1l[i] += __shfl_xor(s1l[i], off);
            el[i]  += __shfl_xor(el[i], off);
        }
    }
    if (tx == 0) {
        #pragma unroll
        for (int i = 0; i < 4; ++i) {
            S1P[c * MM + m0 + my4 + i] = s1l[i];
            EP [c * MM + m0 + my4 + i] = el[i];
        }
    }
    __syncthreads();

    // ---- phase B: A-partials over this chunk, 2-slab register pipeline ----
    if (tid < DP) {
        float a1[16], a2[16];
        #pragma unroll
        for (int m = 0; m < 16; ++m) { a1[m] = 0.f; a2[m] = 0.f; }
        float q0a[4], q0b[4], q1a[4], q1b[4];
        PB_LOAD(q0a, q0b, 0);
        int t4 = 0;
        for (; t4 < CHT - 8; t4 += 8) {         // t4 = 0..48, 7 iters
            PB_LOAD(q1a, q1b, t4 + 4);
            PB_FMA(q0a, q0b, t4);
            PB_LOAD(q0a, q0b, t4 + 8);
            PB_FMA(q1a, q1b, t4 + 4);
        }
        PB_LOAD(q1a, q1b, CHT - 4);
        PB_FMA(q0a, q0b, CHT - 8);
        PB_FMA(q1a, q1b, CHT - 4);
        #pragma unroll
        for (int m = 0; m < 16; ++m) {
            P1[(c * MM + m0 + m) * DP + tid] = a1[m];
            P2[(c * MM + m0 + m) * DP + tid] = a2[m];
        }
    }
}

// ---------- K4: chunk-reduce + final forces + energies ----------
__global__ __launch_bounds__(256) void k4_final(
        const float* __restrict__ Rs, const float* __restrict__ xsp,
        const float* __restrict__ P1, const float* __restrict__ P2,
        const float* __restrict__ S1P, const float* __restrict__ EP,
        float* __restrict__ out) {
    int m = blockIdx.x, tid = threadIdx.x;
    __shared__ float fxs[DD];
    __shared__ float Rl[64];
    __shared__ float sE[2];
    if (tid < NA * 3) Rl[tid] = Rs[m * NA * 3 + tid];
    if (tid >= 64 && tid < 128) {      // wave 1: reduce s1/E over 64 chunks
        int cc = tid - 64;
        float s = S1P[cc * MM + m];
        float e = EP [cc * MM + m];
        #pragma unroll
        for (int off = 32; off >= 1; off >>= 1) {
            s += __shfl_xor(s, off);
            e += __shfl_xor(e, off);
        }
        if (cc == 0) { sE[0] = s; sE[1] = e; }
    }
    float pa = 0.f, pb = 0.f;
    if (tid < DD) {
        for (int cc = 0; cc < NC; ++cc) {
            pa += P1[(cc * MM + m) * DP + tid];
            pb += P2[(cc * MM + m) * DP + tid];
        }
    }
    __syncthreads();
    if (tid < DD)
        fxs[tid] = QF * xsp[m * DP + tid] * sE[0] - QF * pa - pb;
    __syncthreads();
    if (tid < NA * 3) {
        int b = tid / 3, c = tid - b * 3;
        float acc = 0.f;
        #pragma unroll
        for (int a = 0; a < NA; ++a) {
            if (a == b) continue;
            int hi = a > b ? a : b, lo = a > b ? b : a;
            int d = hi * (hi - 1) / 2 + lo;
            float dx = Rl[a * 3 + 0] - Rl[b * 3 + 0];
            float dy = Rl[a * 3 + 1] - Rl[b * 3 + 1];
            float dz = Rl[a * 3 + 2] - Rl[b * 3 + 2];
            float r2 = dx * dx + dy * dy + dz * dz;
            float ir = 1.0f / sqrtf(r2);
            float w = fxs[d] * ir * ir * ir;
            float comp = (c == 0) ? dx : ((c == 1) ? dy : dz);
            acc = fmaf(w, comp, acc);
        }
        out[MM + m * NA * 3 + tid] = acc;
    }
    if (tid == 0) out[m] = sE[1] * INVQ;
}

extern "C" void kernel_launch(void* const* d_in, const int* in_sizes, int n_in,
                              void* d_out, int out_size, void* d_ws, size_t ws_size,
                              hipStream_t stream) {
    const float* Rs = (const float*)d_in[0];
    const float* tr = (const float*)d_in[1];
    const float* jx = (const float*)d_in[2];
    float* out = (float*)d_out;
    float* ws = (float*)d_ws;

    float* trp  = ws + OFF_TRP;
    float* jxp  = ws + OFF_JXP;
    float* trpT = ws + OFF_TRPT;
    float* jxpT = ws + OFF_JXPT;
    float* xsp  = ws + OFF_XSP;
    float* nt   = ws + OFF_NT;
    float* ct   = ws + OFF_CT;
    float* nm   = ws + OFF_NM;
    float* S1P  = ws + OFF_S1P;
    float* EP   = ws + OFF_EP;
    float* P1   = ws + OFF_P1;
    float* P2   = ws + OFF_P2;

    k0_prep<<<256, 256, 0, stream>>>(tr, jx, Rs, trp, jxp, trpT, jxpT, nt, ct, xsp, nm);
    k23_fused<<<dim3(NC, MM / 16), 256, 0, stream>>>(trp, jxp, trpT, jxpT, xsp, nt, ct, nm, S1P, EP, P1, P2);
    k4_final<<<MM, 256, 0, stream>>>(Rs, xsp, P1, P2, S1P, EP, out);
}